// Round 1
// baseline (264.146 us; speedup 1.0000x reference)
//
#include <hip/hip_runtime.h>
#include <math.h>

// x: (16, 4, 128, 64, 64) fp32; w1,w2: (128,128) fp32
// out = x * ca[b,c] * mask[b,c]   (mask = top-103 of ca per batch)

#define B 16
#define F 4
#define C 128
#define HW 4096                  // 64*64
#define BC (B * C)               // 2048
#define PER_BC (F * HW)          // 16384 elements per (b,c)
#define TOPK 103                 // ceil(0.8 * 128)

// ---------------- Kernel 1: per-(b,c) sum + max pool ----------------
__global__ __launch_bounds__(256) void pool_kernel(const float* __restrict__ x,
                                                   float* __restrict__ sums,
                                                   float* __restrict__ maxs) {
    const int bc = blockIdx.x;          // 0..2047
    const int b = bc >> 7;
    const int c = bc & 127;
    const int tid = threadIdx.x;        // 0..255

    float s = 0.0f;
    float m = -INFINITY;
    // For fixed (b,c): F contiguous chunks of HW floats (1024 float4 each).
    // 256 threads -> 4 float4 per thread per f-chunk. Fully coalesced.
    #pragma unroll
    for (int f = 0; f < F; ++f) {
        const float4* p = reinterpret_cast<const float4*>(
            x + ((size_t)((b * F + f) * C + c)) * HW);
        #pragma unroll
        for (int j = 0; j < 4; ++j) {
            float4 v = p[tid + j * 256];
            s += v.x + v.y + v.z + v.w;
            m = fmaxf(m, fmaxf(fmaxf(v.x, v.y), fmaxf(v.z, v.w)));
        }
    }
    // wave64 butterfly reduce
    #pragma unroll
    for (int off = 32; off >= 1; off >>= 1) {
        s += __shfl_xor(s, off);
        m = fmaxf(m, __shfl_xor(m, off));
    }
    __shared__ float ss[4], sm[4];
    const int wave = tid >> 6;
    if ((tid & 63) == 0) { ss[wave] = s; sm[wave] = m; }
    __syncthreads();
    if (tid == 0) {
        float S = ss[0] + ss[1] + ss[2] + ss[3];
        float M = fmaxf(fmaxf(sm[0], sm[1]), fmaxf(sm[2], sm[3]));
        sums[bc] = S;
        maxs[bc] = M;
    }
}

// ---------------- Kernel 2: MLP + sigmoid + top-k mask ----------------
// One block per batch, 128 threads (one per channel).
__global__ __launch_bounds__(128) void mlp_topk_kernel(const float* __restrict__ sums,
                                                       const float* __restrict__ maxs,
                                                       const float* __restrict__ w1,
                                                       const float* __restrict__ w2,
                                                       float* __restrict__ coef) {
    const int b = blockIdx.x;       // 0..15
    const int c = threadIdx.x;      // 0..127

    __shared__ float avg_s[C], max_s[C], h1_s[C], h2_s[C], ca_s[C];

    avg_s[c] = sums[b * C + c] * (1.0f / (float)PER_BC);
    max_s[c] = maxs[b * C + c];
    __syncthreads();

    // h = relu(v @ w1.T):  h[c] = relu(sum_j v[j] * w1[c][j])
    float a1 = 0.0f, a2 = 0.0f;
    #pragma unroll 8
    for (int j = 0; j < C; ++j) {
        float wv = w1[c * C + j];
        a1 += avg_s[j] * wv;
        a2 += max_s[j] * wv;
    }
    h1_s[c] = fmaxf(a1, 0.0f);
    h2_s[c] = fmaxf(a2, 0.0f);
    __syncthreads();

    // o = h @ w2.T
    float o1 = 0.0f, o2 = 0.0f;
    #pragma unroll 8
    for (int j = 0; j < C; ++j) {
        float wv = w2[c * C + j];
        o1 += h1_s[j] * wv;
        o2 += h2_s[j] * wv;
    }
    float z = o1 + o2;
    float ca = 1.0f / (1.0f + expf(-z));
    ca_s[c] = ca;
    __syncthreads();

    // rank = number of values that beat me (strictly greater, or equal with
    // lower index — matches jax.lax.top_k tie-break). Keep if rank < TOPK.
    int rank = 0;
    #pragma unroll 8
    for (int j = 0; j < C; ++j) {
        float v = ca_s[j];
        rank += (v > ca) || (v == ca && j < c);
    }
    coef[b * C + c] = (rank < TOPK) ? ca : 0.0f;
}

// ---------------- Kernel 3: out = x * coef[b,c] ----------------
__global__ __launch_bounds__(256) void scale_kernel(const float* __restrict__ x,
                                                    const float* __restrict__ coef,
                                                    float* __restrict__ out,
                                                    int n4) {
    const int stride = gridDim.x * blockDim.x;
    for (int i = blockIdx.x * blockDim.x + threadIdx.x; i < n4; i += stride) {
        float4 v = reinterpret_cast<const float4*>(x)[i];
        // element index e4 = i*4; e = e4/4096 = i/1024 = (b*F + f)*C + c
        int e = i >> 10;
        int c = e & 127;
        int b = e >> 9;          // e / (F*C) = e / 512
        float s = coef[b * C + c];
        v.x *= s; v.y *= s; v.z *= s; v.w *= s;
        reinterpret_cast<float4*>(out)[i] = v;
    }
}

extern "C" void kernel_launch(void* const* d_in, const int* in_sizes, int n_in,
                              void* d_out, int out_size, void* d_ws, size_t ws_size,
                              hipStream_t stream) {
    const float* x  = (const float*)d_in[0];
    const float* w1 = (const float*)d_in[1];
    const float* w2 = (const float*)d_in[2];
    float* out = (float*)d_out;

    float* sums = (float*)d_ws;          // BC floats
    float* maxs = sums + BC;             // BC floats
    float* coef = maxs + BC;             // BC floats

    pool_kernel<<<BC, 256, 0, stream>>>(x, sums, maxs);
    mlp_topk_kernel<<<B, C, 0, stream>>>(sums, maxs, w1, w2, coef);

    const int n4 = (B * F * C * HW) / 4; // 8,388,608 float4
    scale_kernel<<<2048, 256, 0, stream>>>(x, coef, out, n4);
}

// Round 3
// 261.777 us; speedup vs baseline: 1.0091x; 1.0091x over previous
//
#include <hip/hip_runtime.h>
#include <math.h>

// x: (16, 4, 128, 64, 64) fp32; w1,w2: (128,128) fp32
// out = x * ca[b,c] * mask[b,c]   (mask = top-103 of ca per batch)
// Note x*mask*wta = x*ca*mask since mask is 0/1.

#define B 16
#define F 4
#define C 128
#define HW 4096                  // 64*64
#define BC (B * C)               // 2048
#define NCHUNK (B * F * C)       // 8192 contiguous 16KB chunks
#define PER_BC (F * HW)          // 16384 elements per (b,c)
#define TOPK 103                 // ceil(0.8 * 128)

// native vector type — accepted by __builtin_nontemporal_* (HIP float4 is not)
typedef float f32x4 __attribute__((ext_vector_type(4)));

// ---------------- Kernel 1: per-(b,c) sum + max pool ----------------
// One block per (b,c); reads 4 x 16KB contiguous chunks, fully coalesced.
// Normal (caching) loads on purpose: this pass re-populates L3 with x after
// the harness's 512MiB poison fill evicted it; kernel 3 then reads x from L3.
__global__ __launch_bounds__(256) void pool_kernel(const float* __restrict__ x,
                                                   float* __restrict__ sums,
                                                   float* __restrict__ maxs) {
    const int bc = blockIdx.x;          // 0..2047
    const int b = bc >> 7;
    const int c = bc & 127;
    const int tid = threadIdx.x;        // 0..255

    float s = 0.0f;
    float m = -INFINITY;
    #pragma unroll
    for (int f = 0; f < F; ++f) {
        const f32x4* p = reinterpret_cast<const f32x4*>(
            x + ((size_t)((b * F + f) * C + c)) * HW);
        #pragma unroll
        for (int j = 0; j < 4; ++j) {
            f32x4 v = p[tid + j * 256];
            s += v.x + v.y + v.z + v.w;
            m = fmaxf(m, fmaxf(fmaxf(v.x, v.y), fmaxf(v.z, v.w)));
        }
    }
    // wave64 butterfly reduce
    #pragma unroll
    for (int off = 32; off >= 1; off >>= 1) {
        s += __shfl_xor(s, off);
        m = fmaxf(m, __shfl_xor(m, off));
    }
    __shared__ float ss[4], sm[4];
    const int wave = tid >> 6;
    if ((tid & 63) == 0) { ss[wave] = s; sm[wave] = m; }
    __syncthreads();
    if (tid == 0) {
        sums[bc] = ss[0] + ss[1] + ss[2] + ss[3];
        maxs[bc] = fmaxf(fmaxf(sm[0], sm[1]), fmaxf(sm[2], sm[3]));
    }
}

// ---------------- Kernel 2: MLP + sigmoid + top-k mask ----------------
// One block per batch, 128 threads (one per channel). ~5us, latency-bound.
__global__ __launch_bounds__(128) void mlp_topk_kernel(const float* __restrict__ sums,
                                                       const float* __restrict__ maxs,
                                                       const float* __restrict__ w1,
                                                       const float* __restrict__ w2,
                                                       float* __restrict__ coef) {
    const int b = blockIdx.x;       // 0..15
    const int c = threadIdx.x;      // 0..127

    __shared__ float avg_s[C], max_s[C], h1_s[C], h2_s[C], ca_s[C];

    avg_s[c] = sums[b * C + c] * (1.0f / (float)PER_BC);
    max_s[c] = maxs[b * C + c];
    __syncthreads();

    float a1 = 0.0f, a2 = 0.0f;
    #pragma unroll 8
    for (int j = 0; j < C; ++j) {
        float wv = w1[c * C + j];
        a1 += avg_s[j] * wv;
        a2 += max_s[j] * wv;
    }
    h1_s[c] = fmaxf(a1, 0.0f);
    h2_s[c] = fmaxf(a2, 0.0f);
    __syncthreads();

    float o1 = 0.0f, o2 = 0.0f;
    #pragma unroll 8
    for (int j = 0; j < C; ++j) {
        float wv = w2[c * C + j];
        o1 += h1_s[j] * wv;
        o2 += h2_s[j] * wv;
    }
    float ca = 1.0f / (1.0f + expf(-(o1 + o2)));
    ca_s[c] = ca;
    __syncthreads();

    // rank = # of values that beat me (strictly greater, or equal with lower
    // index — matches jax.lax.top_k tie-break). Keep if rank < TOPK.
    int rank = 0;
    #pragma unroll 8
    for (int j = 0; j < C; ++j) {
        float v = ca_s[j];
        rank += (v > ca) || (v == ca && j < c);
    }
    coef[b * C + c] = (rank < TOPK) ? ca : 0.0f;
}

// ---------------- Kernel 3: out = x * coef[b,c] ----------------
// One block per contiguous 16KB chunk (chunk = (b*F+f)*C + c): coef is
// wave-uniform (scalar load), addressing trivial, loads/stores coalesced.
// Nontemporal stores: out is write-once — keep it from evicting x in L3.
__global__ __launch_bounds__(256) void scale_kernel(const float* __restrict__ x,
                                                    const float* __restrict__ coef,
                                                    float* __restrict__ out) {
    const int chunk = blockIdx.x;        // 0..8191
    const int c = chunk & 127;
    const int b = chunk >> 9;            // chunk / (F*C)
    const float s = coef[b * C + c];

    const f32x4* px = reinterpret_cast<const f32x4*>(x) + (size_t)chunk * 1024;
    f32x4*       po = reinterpret_cast<f32x4*>(out)     + (size_t)chunk * 1024;
    #pragma unroll
    for (int j = 0; j < 4; ++j) {
        f32x4 v = px[threadIdx.x + j * 256];
        v *= s;
        __builtin_nontemporal_store(v, &po[threadIdx.x + j * 256]);
    }
}

extern "C" void kernel_launch(void* const* d_in, const int* in_sizes, int n_in,
                              void* d_out, int out_size, void* d_ws, size_t ws_size,
                              hipStream_t stream) {
    const float* x  = (const float*)d_in[0];
    const float* w1 = (const float*)d_in[1];
    const float* w2 = (const float*)d_in[2];
    float* out = (float*)d_out;

    float* sums = (float*)d_ws;          // BC floats
    float* maxs = sums + BC;             // BC floats
    float* coef = maxs + BC;             // BC floats

    pool_kernel<<<BC, 256, 0, stream>>>(x, sums, maxs);
    mlp_topk_kernel<<<B, C, 0, stream>>>(sums, maxs, w1, w2, coef);
    scale_kernel<<<NCHUNK, 256, 0, stream>>>(x, coef, out);
}

// Round 5
// 254.719 us; speedup vs baseline: 1.0370x; 1.0277x over previous
//
#include <hip/hip_runtime.h>
#include <math.h>

// x: (16, 4, 128, 64, 64) fp32; w1,w2: (128,128) fp32
// out = x * ca[b,c] * mask[b,c]  (mask = top-103 of ca per batch)
// x*mask*wta = x*ca*mask since mask is 0/1.

#define B 16
#define F 4
#define C 128
#define HW 4096                  // 64*64
#define BC (B * C)               // 2048
#define NCHUNK (B * F * C)       // 8192 contiguous 16KB chunks
#define PER_BC (F * HW)          // 16384 elements per (b,c)
#define TOPK 103                 // ceil(0.8 * 128)
#define LDW 129                  // padded LDS leading dim: 129%32==1 -> (c+j)%32 banks, 2-way max (free)

typedef float f32x4 __attribute__((ext_vector_type(4)));

// ---------------- Kernel 1: per-(b,c) sum + max pool ----------------
// One block per (b,c); 4 x 16KB contiguous chunks, coalesced float4.
// Normal (caching) loads on purpose: re-populates L3 with x after the
// harness's poison fills evicted it; kernel 3 then reads x from L3.
__global__ __launch_bounds__(256) void pool_kernel(const float* __restrict__ x,
                                                   float* __restrict__ sums,
                                                   float* __restrict__ maxs) {
    const int bc = blockIdx.x;          // 0..2047
    const int b = bc >> 7;
    const int c = bc & 127;
    const int tid = threadIdx.x;        // 0..255

    // 4 independent accumulator pairs (ILP: no serial dependence across j)
    float s0 = 0, s1 = 0, s2 = 0, s3 = 0;
    float m0 = -INFINITY, m1 = -INFINITY, m2 = -INFINITY, m3 = -INFINITY;
    #pragma unroll
    for (int f = 0; f < F; ++f) {
        const f32x4* p = reinterpret_cast<const f32x4*>(
            x + ((size_t)((b * F + f) * C + c)) * HW);
        f32x4 v0 = p[tid +   0];
        f32x4 v1 = p[tid + 256];
        f32x4 v2 = p[tid + 512];
        f32x4 v3 = p[tid + 768];
        s0 += v0.x + v0.y + v0.z + v0.w;
        s1 += v1.x + v1.y + v1.z + v1.w;
        s2 += v2.x + v2.y + v2.z + v2.w;
        s3 += v3.x + v3.y + v3.z + v3.w;
        m0 = fmaxf(m0, fmaxf(fmaxf(v0.x, v0.y), fmaxf(v0.z, v0.w)));
        m1 = fmaxf(m1, fmaxf(fmaxf(v1.x, v1.y), fmaxf(v1.z, v1.w)));
        m2 = fmaxf(m2, fmaxf(fmaxf(v2.x, v2.y), fmaxf(v2.z, v2.w)));
        m3 = fmaxf(m3, fmaxf(fmaxf(v3.x, v3.y), fmaxf(v3.z, v3.w)));
    }
    float S = (s0 + s1) + (s2 + s3);
    float M = fmaxf(fmaxf(m0, m1), fmaxf(m2, m3));

    #pragma unroll
    for (int off = 32; off >= 1; off >>= 1) {
        S += __shfl_xor(S, off);
        M = fmaxf(M, __shfl_xor(M, off));
    }
    __shared__ float ss[4], sm[4];
    const int wave = tid >> 6;
    if ((tid & 63) == 0) { ss[wave] = S; sm[wave] = M; }
    __syncthreads();
    if (tid == 0) {
        sums[bc] = ss[0] + ss[1] + ss[2] + ss[3];
        maxs[bc] = fmaxf(fmaxf(sm[0], sm[1]), fmaxf(sm[2], sm[3]));
    }
}

// ---------------- Kernel 2: MLP + sigmoid + top-k mask ----------------
// One block per batch, 256 threads. Weights staged coalesced into LDS
// (padded LD=129 -> matvec LDS reads are 2-way/bank = free). The matvec
// itself runs on threads 0..127 (one per channel).
__global__ __launch_bounds__(256) void mlp_topk_kernel(const float* __restrict__ sums,
                                                       const float* __restrict__ maxs,
                                                       const float* __restrict__ w1,
                                                       const float* __restrict__ w2,
                                                       float* __restrict__ coef) {
    const int b = blockIdx.x;       // 0..15
    const int tid = threadIdx.x;    // 0..255

    __shared__ float w1s[C * LDW];  // 64.5 KB
    __shared__ float w2s[C * LDW];  // 64.5 KB  (static 129KB total: OK on gfx950, 160KB/CU)
    __shared__ float avg_s[C], max_s[C], h1_s[C], h2_s[C], ca_s[C];

    // coalesced weight staging: 4096 float4 per matrix, 16 iters of 256 threads
    #pragma unroll
    for (int i = 0; i < 16; ++i) {
        const int v = tid + i * 256;         // float4 index 0..4095
        const int row = v >> 5;              // 32 float4 per row
        const int col = (v & 31) * 4;
        f32x4 a = reinterpret_cast<const f32x4*>(w1)[v];
        f32x4 c4 = reinterpret_cast<const f32x4*>(w2)[v];
        float* p1 = &w1s[row * LDW + col];
        float* p2 = &w2s[row * LDW + col];
        p1[0] = a.x;  p1[1] = a.y;  p1[2] = a.z;  p1[3] = a.w;
        p2[0] = c4.x; p2[1] = c4.y; p2[2] = c4.z; p2[3] = c4.w;
    }
    if (tid < C) {
        avg_s[tid] = sums[b * C + tid] * (1.0f / (float)PER_BC);
        max_s[tid] = maxs[b * C + tid];
    }
    __syncthreads();

    if (tid < C) {
        const int c = tid;
        float a1 = 0.0f, a2 = 0.0f;
        #pragma unroll 8
        for (int j = 0; j < C; ++j) {
            float wv = w1s[c * LDW + j];
            a1 += avg_s[j] * wv;
            a2 += max_s[j] * wv;
        }
        h1_s[c] = fmaxf(a1, 0.0f);
        h2_s[c] = fmaxf(a2, 0.0f);
    }
    __syncthreads();

    if (tid < C) {
        const int c = tid;
        float o1 = 0.0f, o2 = 0.0f;
        #pragma unroll 8
        for (int j = 0; j < C; ++j) {
            float wv = w2s[c * LDW + j];
            o1 += h1_s[j] * wv;
            o2 += h2_s[j] * wv;
        }
        ca_s[c] = 1.0f / (1.0f + expf(-(o1 + o2)));
    }
    __syncthreads();

    if (tid < C) {
        const int c = tid;
        const float ca = ca_s[c];
        // rank = # of values that beat me (strictly greater, or equal with
        // lower index — matches jax.lax.top_k tie-break). Keep if rank < TOPK.
        int rank = 0;
        #pragma unroll 8
        for (int j = 0; j < C; ++j) {
            float v = ca_s[j];
            rank += (v > ca) || (v == ca && j < c);
        }
        coef[b * C + c] = (rank < TOPK) ? ca : 0.0f;
    }
}

// ---------------- Kernel 3: out = x * coef[b,c] ----------------
// One block per contiguous 16KB chunk: coef is wave-uniform (scalar load).
// Zero-coef chunks (25/128 channels): skip the x read entirely, store zeros
// (x is finite, so x*0 == 0 exactly). Saves ~19.5% of the fetch.
// Nontemporal stores: out is write-once — keep it from evicting x in L3.
__global__ __launch_bounds__(256) void scale_kernel(const float* __restrict__ x,
                                                    const float* __restrict__ coef,
                                                    float* __restrict__ out) {
    const int chunk = blockIdx.x;        // 0..8191
    const int c = chunk & 127;
    const int b = chunk >> 9;            // chunk / (F*C)
    const float s = coef[b * C + c];

    f32x4* po = reinterpret_cast<f32x4*>(out) + (size_t)chunk * 1024;
    if (s == 0.0f) {                     // block-uniform branch, no divergence
        const f32x4 z = {0.0f, 0.0f, 0.0f, 0.0f};
        #pragma unroll
        for (int j = 0; j < 4; ++j)
            __builtin_nontemporal_store(z, &po[threadIdx.x + j * 256]);
        return;
    }
    const f32x4* px = reinterpret_cast<const f32x4*>(x) + (size_t)chunk * 1024;
    #pragma unroll
    for (int j = 0; j < 4; ++j) {
        f32x4 v = px[threadIdx.x + j * 256];
        v *= s;
        __builtin_nontemporal_store(v, &po[threadIdx.x + j * 256]);
    }
}

extern "C" void kernel_launch(void* const* d_in, const int* in_sizes, int n_in,
                              void* d_out, int out_size, void* d_ws, size_t ws_size,
                              hipStream_t stream) {
    const float* x  = (const float*)d_in[0];
    const float* w1 = (const float*)d_in[1];
    const float* w2 = (const float*)d_in[2];
    float* out = (float*)d_out;

    float* sums = (float*)d_ws;          // BC floats
    float* maxs = sums + BC;             // BC floats
    float* coef = maxs + BC;             // BC floats

    pool_kernel<<<BC, 256, 0, stream>>>(x, sums, maxs);
    mlp_topk_kernel<<<B, 256, 0, stream>>>(sums, maxs, w1, w2, coef);
    scale_kernel<<<NCHUNK, 256, 0, stream>>>(x, coef, out);
}